// Round 4
// baseline (1694.856 us; speedup 1.0000x reference)
//
#include <hip/hip_runtime.h>

#define SS    4096   // sequence length
#define DK    16     // head dim
#define NB    4      // batch
#define TQ    2      // query rows per block
#define BLOCK 256
#define NJ    4      // float4 column-groups per thread (16 cols total)

typedef float fx4 __attribute__((ext_vector_type(4)));
typedef int   ix4 __attribute__((ext_vector_type(4)));

// ---- runtime mask-dtype probe --------------------------------------------
// int32 mask: every 4-byte word is exactly 0 or 1.
// uint8 mask: words pack 4 bools -> high bytes nonzero w/ prob ~1.
__global__ void detect_mask_dtype(const unsigned* __restrict__ m,
                                  int* __restrict__ flag)
{
    unsigned acc = 0;
    for (int i = 0; i < 1024; ++i) acc |= m[i];
    *flag = (acc > 1u) ? 1 : 0;    // 1 => byte-packed bools
}

__global__ __launch_bounds__(BLOCK, 4)
void attn_fused(const float* __restrict__ Qm, const float* __restrict__ Km,
                const float* __restrict__ Vm, const void*  __restrict__ Mraw,
                const float* __restrict__ Lm, const float* __restrict__ WP,
                const float* __restrict__ BP, const int*   __restrict__ flagp,
                float* __restrict__ Co, float* __restrict__ Ao)
{
    __shared__ float redl[4][TQ];
    __shared__ float redc[4][TQ][DK];

    const int tid = threadIdx.x;
    const int b   = blockIdx.x >> 11;            // 2048 blocks per batch
    const int q0  = (blockIdx.x & 2047) * TQ;

    const bool  m8 = (*flagp != 0);              // block-uniform branch
    const float sw = WP[0];
    const float sb = BP[0];

    const float* qp = Qm + ((size_t)b * SS + q0) * DK;
    const float* kp = Km + (size_t)b * SS * DK;
    const float* vp = Vm + (size_t)b * SS * DK;
    const size_t mrow = (size_t)b * SS * SS + (size_t)q0 * SS;
    const int*           mp32 = (const int*)Mraw           + mrow;
    const unsigned char* mp8  = (const unsigned char*)Mraw + mrow;
    const float* lp = Lm + mrow;
    float*       ap = Ao + mrow;

    // ---- Q rows are block-uniform: pin into SGPRs (bit-cast readfirstlane)
    float qreg[TQ][DK];
    #pragma unroll
    for (int qq = 0; qq < TQ; ++qq)
        #pragma unroll
        for (int d = 0; d < DK; ++d)
            qreg[qq][d] = __uint_as_float(
                __builtin_amdgcn_readfirstlane(__float_as_uint(qp[qq * DK + d])));

    float p[TQ][4 * NJ];                 // 32 VGPRs
    float lsum[TQ] = {0.f, 0.f};

    // ---- Phase 1: scores -> exp. Interleaved mapping: column group
    //      c = (j*BLOCK + tid)*4  => each wave instruction touches 1 KB
    //      fully contiguous (perfect coalescing).
    #pragma unroll
    for (int j = 0; j < NJ; ++j) {
        const int c = (j * BLOCK + tid) * 4;

        unsigned mu[TQ];
        ix4      mi[TQ];
        fx4      li[TQ];
        if (m8) {
            #pragma unroll
            for (int qq = 0; qq < TQ; ++qq)
                mu[qq] = __builtin_nontemporal_load(
                             (const unsigned*)(mp8 + (size_t)qq * SS + c));
        } else {
            #pragma unroll
            for (int qq = 0; qq < TQ; ++qq)
                mi[qq] = __builtin_nontemporal_load(
                             (const ix4*)(mp32 + (size_t)qq * SS + c));
        }
        #pragma unroll
        for (int qq = 0; qq < TQ; ++qq)
            li[qq] = __builtin_nontemporal_load(
                         (const fx4*)(lp + (size_t)qq * SS + c));

        #pragma unroll
        for (int u = 0; u < 4; ++u) {
            const int k = c + u;
            const fx4 ka = *(const fx4*)(kp + (size_t)k * DK + 0);
            const fx4 kb = *(const fx4*)(kp + (size_t)k * DK + 4);
            const fx4 kc = *(const fx4*)(kp + (size_t)k * DK + 8);
            const fx4 kd = *(const fx4*)(kp + (size_t)k * DK + 12);
            #pragma unroll
            for (int qq = 0; qq < TQ; ++qq) {
                const float* q = qreg[qq];
                float s;
                s = fmaf(q[0],  ka.x, 0.f);
                s = fmaf(q[1],  ka.y, s);  s = fmaf(q[2],  ka.z, s);
                s = fmaf(q[3],  ka.w, s);  s = fmaf(q[4],  kb.x, s);
                s = fmaf(q[5],  kb.y, s);  s = fmaf(q[6],  kb.z, s);
                s = fmaf(q[7],  kb.w, s);  s = fmaf(q[8],  kc.x, s);
                s = fmaf(q[9],  kc.y, s);  s = fmaf(q[10], kc.z, s);
                s = fmaf(q[11], kc.w, s);  s = fmaf(q[12], kd.x, s);
                s = fmaf(q[13], kd.y, s);  s = fmaf(q[14], kd.z, s);
                s = fmaf(q[15], kd.w, s);
                const float lv = (u == 0) ? li[qq].x : (u == 1) ? li[qq].y
                                : (u == 2) ? li[qq].z : li[qq].w;
                const int mv = m8
                    ? (int)((mu[qq] >> (8 * u)) & 0xffu)
                    : ((u == 0) ? mi[qq].x : (u == 1) ? mi[qq].y
                     : (u == 2) ? mi[qq].z : mi[qq].w);
                s = s * 0.25f + fmaf(sw, lv, sb);
                const float e  = __expf(s);
                const float pv = mv ? 0.f : e;   // mask==true -> -1e9 -> 0
                p[qq][4 * j + u] = pv;
                lsum[qq] += pv;
            }
        }
    }

    // ---- Phase 2: row-sum reduction -----------------------------------
    const int lane = tid & 63;
    const int wv   = tid >> 6;
    #pragma unroll
    for (int qq = 0; qq < TQ; ++qq) {
        float v = lsum[qq];
        #pragma unroll
        for (int off = 32; off; off >>= 1)
            v += __shfl_down(v, off);
        lsum[qq] = v;
    }
    if (lane == 0) {
        #pragma unroll
        for (int qq = 0; qq < TQ; ++qq)
            redl[wv][qq] = lsum[qq];
    }
    __syncthreads();
    float rl[TQ];
    #pragma unroll
    for (int qq = 0; qq < TQ; ++qq)
        rl[qq] = 1.0f / (redl[0][qq] + redl[1][qq] + redl[2][qq] + redl[3][qq]);

    // ---- Phase 3: normalize, store attn (full-line NT stores), PV ------
    float ctx[TQ][DK];                   // 32 VGPRs
    #pragma unroll
    for (int qq = 0; qq < TQ; ++qq)
        #pragma unroll
        for (int d = 0; d < DK; ++d)
            ctx[qq][d] = 0.f;

    #pragma unroll
    for (int j = 0; j < NJ; ++j) {
        const int c = (j * BLOCK + tid) * 4;
        #pragma unroll
        for (int u = 0; u < 4; ++u) {
            const int k = c + u;
            const fx4 va = *(const fx4*)(vp + (size_t)k * DK + 0);
            const fx4 vb = *(const fx4*)(vp + (size_t)k * DK + 4);
            const fx4 vc = *(const fx4*)(vp + (size_t)k * DK + 8);
            const fx4 vd = *(const fx4*)(vp + (size_t)k * DK + 12);
            #pragma unroll
            for (int qq = 0; qq < TQ; ++qq) {
                const float pn = p[qq][4 * j + u] * rl[qq];
                p[qq][4 * j + u] = pn;
                ctx[qq][0]  = fmaf(pn, va.x, ctx[qq][0]);
                ctx[qq][1]  = fmaf(pn, va.y, ctx[qq][1]);
                ctx[qq][2]  = fmaf(pn, va.z, ctx[qq][2]);
                ctx[qq][3]  = fmaf(pn, va.w, ctx[qq][3]);
                ctx[qq][4]  = fmaf(pn, vb.x, ctx[qq][4]);
                ctx[qq][5]  = fmaf(pn, vb.y, ctx[qq][5]);
                ctx[qq][6]  = fmaf(pn, vb.z, ctx[qq][6]);
                ctx[qq][7]  = fmaf(pn, vb.w, ctx[qq][7]);
                ctx[qq][8]  = fmaf(pn, vc.x, ctx[qq][8]);
                ctx[qq][9]  = fmaf(pn, vc.y, ctx[qq][9]);
                ctx[qq][10] = fmaf(pn, vc.z, ctx[qq][10]);
                ctx[qq][11] = fmaf(pn, vc.w, ctx[qq][11]);
                ctx[qq][12] = fmaf(pn, vd.x, ctx[qq][12]);
                ctx[qq][13] = fmaf(pn, vd.y, ctx[qq][13]);
                ctx[qq][14] = fmaf(pn, vd.z, ctx[qq][14]);
                ctx[qq][15] = fmaf(pn, vd.w, ctx[qq][15]);
            }
        }
        #pragma unroll
        for (int qq = 0; qq < TQ; ++qq) {
            fx4 st = {p[qq][4 * j + 0], p[qq][4 * j + 1],
                      p[qq][4 * j + 2], p[qq][4 * j + 3]};
            __builtin_nontemporal_store(st,
                (fx4*)(ap + (size_t)qq * SS + c));
        }
    }

    // ---- Phase 4: context reduction ------------------------------------
    #pragma unroll
    for (int qq = 0; qq < TQ; ++qq)
        #pragma unroll
        for (int d = 0; d < DK; ++d) {
            float v = ctx[qq][d];
            #pragma unroll
            for (int off = 32; off; off >>= 1)
                v += __shfl_down(v, off);
            ctx[qq][d] = v;
        }
    if (lane == 0) {
        #pragma unroll
        for (int qq = 0; qq < TQ; ++qq)
            #pragma unroll
            for (int d = 0; d < DK; ++d)
                redc[wv][qq][d] = ctx[qq][d];
    }
    __syncthreads();
    if (tid < TQ * DK) {
        const int qq = tid >> 4;
        const int d  = tid & 15;
        const float v = redc[0][qq][d] + redc[1][qq][d]
                      + redc[2][qq][d] + redc[3][qq][d];
        Co[((size_t)b * SS + q0 + qq) * DK + d] = v;
    }
}

extern "C" void kernel_launch(void* const* d_in, const int* in_sizes, int n_in,
                              void* d_out, int out_size, void* d_ws, size_t ws_size,
                              hipStream_t stream)
{
    (void)in_sizes; (void)n_in; (void)ws_size; (void)out_size;

    const float* Q  = (const float*)d_in[0];
    const float* K  = (const float*)d_in[1];
    const float* V  = (const float*)d_in[2];
    const void*  M  = d_in[3];
    const float* L  = (const float*)d_in[4];
    const float* W  = (const float*)d_in[5];
    const float* Bp = (const float*)d_in[6];

    int* flag = (int*)d_ws;   // rewritten by detect kernel every launch

    float* Co = (float*)d_out;                              // context [4,1,4096,16]
    float* Ao = (float*)d_out + (size_t)NB * SS * DK;       // attn    [4,1,4096,4096]

    detect_mask_dtype<<<1, 1, 0, stream>>>((const unsigned*)M, flag);

    dim3 grid(NB * SS / TQ);   // 8192 blocks
    dim3 block(BLOCK);
    attn_fused<<<grid, block, 0, stream>>>(Q, K, V, M, L, W, Bp, flag, Co, Ao);
}